// Round 5
// baseline (211.426 us; speedup 1.0000x reference)
//
#include <hip/hip_runtime.h>
#include <math.h>

// Problem constants (fixed by setup_inputs)
#define BB 8
#define TT 8
#define NN 196
#define DD 768
#define HH 12
#define HD 64
#define TN (TT * NN)   // 1568
#define MM (BB * TN)   // 12544
#define D3 (3 * DD)    // 2304

typedef _Float16 f16;
typedef _Float16 f16x8 __attribute__((ext_vector_type(8)));
typedef _Float16 f16x4 __attribute__((ext_vector_type(4)));
typedef float f32x4 __attribute__((ext_vector_type(4)));
typedef float f32x16 __attribute__((ext_vector_type(16)));
typedef unsigned int u32;

// async global->LDS, 16B per lane; LDS dest must be wave-uniform base + lane*16
#define GLDS16(gp, lp)                                                        \
  __builtin_amdgcn_global_load_lds(                                           \
      (const __attribute__((address_space(1))) u32*)(gp),                     \
      (__attribute__((address_space(3))) u32*)(lp), 16, 0, 0)

#define MFMA16(a, b, c) __builtin_amdgcn_mfma_f32_16x16x32_f16(a, b, c, 0, 0, 0)
#define MFMA32(a, b, c) __builtin_amdgcn_mfma_f32_32x32x16_f16(a, b, c, 0, 0, 0)
#define SBAR() __builtin_amdgcn_s_barrier()
#define SCHED() __builtin_amdgcn_sched_barrier(0)
#define PBAR()  do { SCHED(); SBAR(); SCHED(); } while (0)

// ---------------------------------------------------------------------------
// 256x256 8-phase fp16 GEMM template, K = 768 fixed (both GEMMs share it).
// R5: MFMA shape switched 16x16x32 -> 32x32x16 f16 (+11% matrix rate, half
// the MFMA instruction count). Staging/swizzle/schedule identical to R1/R4.
// C = A[12544][768] @ Bt[NTN*256][768]^T
// MODE 1 (qkv): fp16 out scattered to qkv tile layout; NTN=9 (441 blocks)
// MODE 0 (proj): fp32 out token-major + bias;          NTN=3 (147 blocks)
// 512 threads = 8 waves (2M x 4N), per-wave 128x64 out = acc[4][2] f32x16
// (mt in 0..3 = 32-row tiles, nt in 0..1 = 32-col tiles).
// Fragments (32x32x16): A row = lane&31, k = (lane>>5)*8+j; B col = lane&31,
// same k. C/D: col=lane&31, row=4*(lane>>5)+(reg&3)+8*(reg>>2)  [m74/m101].
// LDS 128 KiB: As/Bs = 2 dbuf x [256][64] f16, chunk-XOR swizzle by (row&7)
// absorbed into the global source address; reader chunk = (2ks+q2)^(lane&7).
// Schedule per K-tile t (4 phases; raw s_barrier, counted vmcnt):
//   F1: read af(mt0-1,ks0-3)+bf0 | stage A-h0(t+1)->buf^1 | bar | 8 MFMA | bar
//   F2: read bf1                 | stage A-h1(t+1)->buf^1 | bar | 8 MFMA | bar
//   F3: re-read af(mt2-3)        | stage B-h0(t+2)->buf   | bar | 8 MFMA | bar
//   F4: (no reads)          | stage B-h1(t+2)->buf | vmcnt(4) | bar | 8 | bar
// B-halves of the in-use buffer fully read by F2's closing barrier; A by F3.
// vmcnt(4) leaves exactly the two t+2 B half-tiles in flight (never 0).
// Tail staging clamps the tile index (uniform vmcnt counts; dups unread).
// ---------------------------------------------------------------------------
#define GK DD    // 768
#define GNT 12   // K tiles of 64

template <int MODE, int NTN>
__global__ __launch_bounds__(512, 2) void gemm256(
    const f16* __restrict__ A, const f16* __restrict__ Bt,
    f16* __restrict__ C16, float* __restrict__ C32,
    const float* __restrict__ bias) {
  __shared__ f16 As[2 * 256 * 64];
  __shared__ f16 Bs[2 * 256 * 64];

  // bijective XCD swizzle over 49*NTN blocks
  const int nwg = 49 * NTN;
  const int orig = blockIdx.x;
  const int xcd = orig & 7;
  const int inner = orig >> 3;
  const int qq = nwg >> 3;
  const int rr = nwg & 7;
  const int swzid =
      ((xcd < rr) ? xcd * (qq + 1) : rr * (qq + 1) + (xcd - rr) * qq) + inner;
  const int bm = (swzid / NTN) * 256;
  const int bn = (swzid % NTN) * 256;

  const int tid = threadIdx.x;
  const int lane = tid & 63;
  const int wave = tid >> 6;      // 0..7
  const int wy = wave >> 2;       // 0..1  (M half)
  const int wx = wave & 3;        // 0..3  (N quarter)
  const int m2 = lane & 31;       // 32-dim index within fragment
  const int q2 = lane >> 5;       // k-half selector

  // --- staging: thread handles phys chunks {tid, tid+512} of each 128x64
  // half-tile; row = chunk>>3 (+64), phys slot = chunk&7,
  // logical chunk = slot ^ (row&7) pre-applied to the GLOBAL address.
  const int sr = tid >> 3;                 // 0..63
  const int sc = (tid & 7) ^ (sr & 7);
  const f16* gA = A + (size_t)(bm + sr) * GK + sc * 8;
  const f16* gB = Bt + (size_t)(bn + sr) * GK + sc * 8;
  f16* lA = &As[tid * 8];
  f16* lB = &Bs[tid * 8];

#define STAGE_A(db, h, tile)                                   \
  do {                                                         \
    const f16* _s = gA + (size_t)(h) * 128 * GK + (tile) * 64; \
    f16* _d = lA + (db) * 16384 + (h) * 8192;                  \
    GLDS16(_s, _d);                                            \
    GLDS16(_s + 64 * GK, _d + 4096);                           \
  } while (0)
#define STAGE_B(db, h, tile)                                   \
  do {                                                         \
    const f16* _s = gB + (size_t)(h) * 128 * GK + (tile) * 64; \
    f16* _d = lB + (db) * 16384 + (h) * 8192;                  \
    GLDS16(_s, _d);                                            \
    GLDS16(_s + 64 * GK, _d + 4096);                           \
  } while (0)

  // --- fragment read addressing: row = base32 + m2 (base32 % 32 == 0), so
  // row&7 == m2&7; logical k-chunk for (ks,q2) = 2ks+q2, phys = ^(m2&7).
  const int sw = m2 & 7;
  int ck[4];
#pragma unroll
  for (int ks = 0; ks < 4; ks++) ck[ks] = ((2 * ks + q2) ^ sw) * 8;
  const f16* rA = &As[(wy * 128 + m2) * 64];
  const f16* rB = &Bs[(wx * 64 + m2) * 64];

  // --- prologue: A(0),B(0) then B(1); allow B(1) (4 loads) outstanding
  STAGE_A(0, 0, 0);
  STAGE_A(0, 1, 0);
  STAGE_B(0, 0, 0);
  STAGE_B(0, 1, 0);
  STAGE_B(1, 0, 1);
  STAGE_B(1, 1, 1);

  f32x16 acc[4][2];
#pragma unroll
  for (int i = 0; i < 4; i++)
#pragma unroll
    for (int j = 0; j < 2; j++) acc[i][j] = (f32x16)0.0f;

  SCHED();
  asm volatile("s_waitcnt vmcnt(4)" ::: "memory");
  SCHED();
  SBAR();
  SCHED();

#pragma unroll 2
  for (int t = 0; t < GNT; ++t) {
    const int db = t & 1;
    const f16* pA = rA + db * 16384;
    const f16* pB = rB + db * 16384;
    const int tA = (t + 1 < GNT) ? t + 1 : GNT - 1;
    const int tB = (t + 2 < GNT) ? t + 2 : GNT - 1;

    f16x8 af[2][4], bf0[4], bf1[4];

    // ---- Phase 1: af(mt0-1) + bf0(nt0); stage A-h0(t+1)
#pragma unroll
    for (int i = 0; i < 2; i++)
#pragma unroll
      for (int ks = 0; ks < 4; ks++)
        af[i][ks] = *(const f16x8*)(pA + i * 2048 + ck[ks]);
#pragma unroll
    for (int ks = 0; ks < 4; ks++)
      bf0[ks] = *(const f16x8*)(pB + ck[ks]);
    STAGE_A(db ^ 1, 0, tA);
    PBAR();
    __builtin_amdgcn_s_setprio(1);
#pragma unroll
    for (int ks = 0; ks < 4; ks++)
#pragma unroll
      for (int i = 0; i < 2; i++)
        acc[i][0] = MFMA32(af[i][ks], bf0[ks], acc[i][0]);
    __builtin_amdgcn_s_setprio(0);
    PBAR();

    // ---- Phase 2: bf1(nt1); stage A-h1(t+1)
#pragma unroll
    for (int ks = 0; ks < 4; ks++)
      bf1[ks] = *(const f16x8*)(pB + 2048 + ck[ks]);
    STAGE_A(db ^ 1, 1, tA);
    PBAR();
    __builtin_amdgcn_s_setprio(1);
#pragma unroll
    for (int ks = 0; ks < 4; ks++)
#pragma unroll
      for (int i = 0; i < 2; i++)
        acc[i][1] = MFMA32(af[i][ks], bf1[ks], acc[i][1]);
    __builtin_amdgcn_s_setprio(0);
    PBAR();

    // ---- Phase 3: re-read af as mt2-3 (A reads of this buf complete here);
    //      stage B-h0(t+2) into CURRENT buf (B reads done by P2 end)
#pragma unroll
    for (int i = 0; i < 2; i++)
#pragma unroll
      for (int ks = 0; ks < 4; ks++)
        af[i][ks] = *(const f16x8*)(pA + (2 + i) * 2048 + ck[ks]);
    STAGE_B(db, 0, tB);
    PBAR();
    __builtin_amdgcn_s_setprio(1);
#pragma unroll
    for (int ks = 0; ks < 4; ks++)
#pragma unroll
      for (int i = 0; i < 2; i++)
        acc[2 + i][1] = MFMA32(af[i][ks], bf1[ks], acc[2 + i][1]);
    __builtin_amdgcn_s_setprio(0);
    PBAR();

    // ---- Phase 4: stage B-h1(t+2); counted vmcnt (A(t+1)+older must land,
    //      B(t+2) pair stays in flight)
    STAGE_B(db, 1, tB);
    SCHED();
    asm volatile("s_waitcnt vmcnt(4)" ::: "memory");
    PBAR();
    __builtin_amdgcn_s_setprio(1);
#pragma unroll
    for (int ks = 0; ks < 4; ks++)
#pragma unroll
      for (int i = 0; i < 2; i++)
        acc[2 + i][0] = MFMA32(af[i][ks], bf0[ks], acc[2 + i][0]);
    __builtin_amdgcn_s_setprio(0);
    PBAR();
  }

  // ---- epilogue (C/D 32x32: col=lane&31, row=4*q2+(j&3)+8*(j>>2))
  const int col0 = bn + wx * 64;
  if constexpr (MODE == 1) {
    // qkv scatter: precompute per-nt column offsets (token-independent)
    size_t coff[2];
#pragma unroll
    for (int nt = 0; nt < 2; nt++) {
      const int col = col0 + nt * 32 + m2;
      const int qt = col / DD;
      const int rem = col - qt * DD;
      const int hh = rem >> 6;
      const int d = rem & 63;
      coff[nt] = (size_t)(hh * 3 + qt) * (NN * 64) + d;
    }
#pragma unroll
    for (int mt = 0; mt < 4; mt++) {
      const int rbase = bm + wy * 128 + mt * 32 + q2 * 4;
#pragma unroll
      for (int j = 0; j < 16; j++) {
        const int token = rbase + (j & 3) + 8 * (j >> 2);
        const int f = token / NN;
        const int n = token - f * NN;
        f16* fb = C16 + ((size_t)f * (HH * 3)) * (NN * 64) + n * 64;
        fb[coff[0]] = (f16)acc[mt][0][j];
        fb[coff[1]] = (f16)acc[mt][1][j];
      }
    }
  } else {
    // proj: token-major fp32 + bias
    const float bv0 = bias[col0 + m2];
    const float bv1 = bias[col0 + 32 + m2];
#pragma unroll
    for (int mt = 0; mt < 4; mt++) {
      const int rbase = bm + wy * 128 + mt * 32 + q2 * 4;
#pragma unroll
      for (int j = 0; j < 16; j++) {
        const int token = rbase + (j & 3) + 8 * (j >> 2);
        float* crow = C32 + (size_t)token * (NTN * 256);
        crow[col0 + m2] = acc[mt][0][j] + bv0;
        crow[col0 + 32 + m2] = acc[mt][1][j] + bv1;
      }
    }
  }
#undef STAGE_A
#undef STAGE_B
}

// ---------------------------------------------------------------------------
// prep: fused input conversion + both weight transposes (one launch).
// segment 0: x fp32 -> xh fp16 (grid-stride, float4)
// segment 1: w_qkv [768][2304] fp32 -> wqkvT [2304][768] fp16
// segment 2: w_proj [768][768] fp32 -> wprojT [768][768] fp16
// ---------------------------------------------------------------------------
#define CONV_BLOCKS 2048
#define TQ_BLOCKS ((D3 / 32) * (DD / 32))  // 72*24 = 1728
#define TP_BLOCKS ((DD / 32) * (DD / 32))  // 24*24 = 576
#define PREP_BLOCKS (CONV_BLOCKS + TQ_BLOCKS + TP_BLOCKS)  // 4352

__global__ __launch_bounds__(256) void prep(
    const float* __restrict__ x, f16* __restrict__ xh,
    const float* __restrict__ w_qkv, f16* __restrict__ wqkvT,
    const float* __restrict__ w_proj, f16* __restrict__ wprojT) {
  __shared__ float tileS[32][33];
  const int bid = blockIdx.x;
  if (bid < CONV_BLOCKS) {
    const int n4 = MM * DD / 4;
    int i = bid * 256 + threadIdx.x;
    const int stride = CONV_BLOCKS * 256;
    for (; i < n4; i += stride) {
      float4 f = ((const float4*)x)[i];
      f16x4 h;
      h[0] = (f16)f.x;
      h[1] = (f16)f.y;
      h[2] = (f16)f.z;
      h[3] = (f16)f.w;
      ((f16x4*)xh)[i] = h;
    }
    return;
  }
  const float* W;
  f16* Wt;
  int Ncol, id;
  if (bid < CONV_BLOCKS + TQ_BLOCKS) {
    id = bid - CONV_BLOCKS;
    W = w_qkv;
    Wt = wqkvT;
    Ncol = D3;
  } else {
    id = bid - CONV_BLOCKS - TQ_BLOCKS;
    W = w_proj;
    Wt = wprojT;
    Ncol = DD;
  }
  const int nx = Ncol / 32;
  const int n0 = (id % nx) * 32;
  const int k0 = (id / nx) * 32;
  const int tx = threadIdx.x & 31, ty = threadIdx.x >> 5;
#pragma unroll
  for (int i = 0; i < 4; i++)
    tileS[ty + i * 8][tx] = W[(size_t)(k0 + ty + i * 8) * Ncol + n0 + tx];
  __syncthreads();
#pragma unroll
  for (int i = 0; i < 4; i++)
    Wt[(size_t)(n0 + ty + i * 8) * DD + k0 + tx] = (f16)tileS[tx][ty + i * 8];
}

// ---------------------------------------------------------------------------
// MFMA attention per (b,h,t), 512 threads (8 waves).  (FROZEN this round so
// any top-5 change is attributable to the GEMM MFMA-shape switch.)
// ---------------------------------------------------------------------------
#define VSTR 232

__global__ __launch_bounds__(512, 4) void attn_mfma(
    const f16* __restrict__ qkv, f16* __restrict__ out) {
  __shared__ f16 KS[196 * 64];
  __shared__ f16 VS[64 * VSTR];
  __shared__ __align__(16) f16 PS[8 * 16 * 40];
  __shared__ float vmean[64];
  float* red = (float*)PS;  // red used strictly before PS (barrier between)

  const int bi = blockIdx.x;  // b*H*T + h*T + t
  const int t = bi % TT;
  const int h = (bi / TT) % HH;
  const int b = bi / (TT * HH);
  const int frame = b * TT + t;
  const int tok0 = frame * NN;

  const f16* Qb = qkv + (size_t)(frame * HH + h) * 3 * NN * 64;
  const f16* Kb = Qb + NN * 64;
  const f16* Vb = Qb + 2 * NN * 64;

  const int tid = threadIdx.x;
  const int lane = tid & 63;
  const int wave = tid >> 6;  // 0..7
  const int m = lane & 15;
  const int q = lane >> 4;

#pragma unroll
  for (int it = 0; it < 3; it++) {
    int chunk = tid + it * 512;
    int row = chunk >> 3, pc = chunk & 7;
    int c = pc ^ (row & 7);
    GLDS16(Kb + row * 64 + c * 8, &KS[chunk * 8]);
  }
  if (tid < 32) {
    int chunk = 1536 + tid;
    int row = chunk >> 3, pc = chunk & 7;
    int c = pc ^ (row & 7);
    *(f16x8*)&KS[chunk * 8] = *(const f16x8*)(Kb + row * 64 + c * 8);
  }

  for (int idx = tid; idx < 64 * 9; idx += 512) {
    int d = idx / 9, c = idx % 9;
    *(f16x4*)&VS[d * VSTR + 196 + c * 4] = (f16x4){0, 0, 0, 0};
  }

  const int vd = tid & 63;
  const int kb = tid >> 6;
  float vpart = 0.0f;
  if (kb < 7) {
#pragma unroll
    for (int it = 0; it < 7; it++) {
      int k0 = kb * 28 + it * 4;
      f16x4 pk;
#pragma unroll
      for (int j = 0; j < 4; j++) {
        f16 v = Vb[(k0 + j) * 64 + vd];
        pk[j] = v;
        vpart += (float)v;
      }
      *(f16x4*)&VS[vd * VSTR + k0] = pk;
    }
  }
  red[tid] = vpart;
  __syncthreads();
  if (tid < 64) {
    float s = 0.0f;
#pragma unroll
    for (int g = 0; g < 8; g++) s += red[tid + 64 * g];
    vmean[tid] = s * (1.0f / (float)NN);
  }
  __syncthreads();

  f16* PSw = &PS[wave * 640];

  for (int qt = wave; qt < 13; qt += 8) {
    const int q0 = qt * 16;
    int qrow = q0 + m;
    if (qrow > NN - 1) qrow = NN - 1;
    const f16* qbase = Qb + qrow * 64;
    f16x8 aq0 = *(const f16x8*)(qbase + q * 8);
    f16x8 aq1 = *(const f16x8*)(qbase + 32 + q * 8);

    f32x4 o0 = (f32x4)0.0f, o1 = (f32x4)0.0f, o2 = (f32x4)0.0f,
          o3 = (f32x4)0.0f;
    float l[4] = {0.0f, 0.0f, 0.0f, 0.0f};

    for (int ch = 0; ch < 7; ch++) {
      const int keyA = ch * 32 + m;
      const int keyB = keyA + 16;
      const int kA = keyA > 195 ? 195 : keyA;
      const int kB = keyB > 195 ? 195 : keyB;
      const int swA = kA & 7, swB = kB & 7;
      f16x8 b00 = *(const f16x8*)&KS[kA * 64 + ((q ^ swA) * 8)];
      f16x8 b01 = *(const f16x8*)&KS[kA * 64 + (((q + 4) ^ swA) * 8)];
      f16x8 b10 = *(const f16x8*)&KS[kB * 64 + ((q ^ swB) * 8)];
      f16x8 b11 = *(const f16x8*)&KS[kB * 64 + (((q + 4) ^ swB) * 8)];
      f32x4 z = (f32x4)0.0f;
      f32x4 s0 = MFMA16(aq0, b00, z);
      s0 = MFMA16(aq1, b01, s0);
      f32x4 s1 = MFMA16(aq0, b10, z);
      s1 = MFMA16(aq1, b11, s1);

      const bool v0 = keyA < NN;
      const bool v1 = keyB < NN;
#pragma unroll
      for (int r = 0; r < 4; r++) {
        float p0 = v0 ? __expf(s0[r] * 0.125f) : 0.0f;
        float p1 = v1 ? __expf(s1[r] * 0.125f) : 0.0f;
        l[r] += p0 + p1;
        PSw[(q * 4 + r) * 40 + m] = (f16)p0;
        PSw[(q * 4 + r) * 40 + 16 + m] = (f16)p1;
      }
      f16x8 pa = *(const f16x8*)&PSw[m * 40 + q * 8];
      f16x8 bv0 = *(const f16x8*)&VS[(0 * 16 + m) * VSTR + ch * 32 + q * 8];
      f16x8 bv1 = *(const f16x8*)&VS[(1 * 16 + m) * VSTR + ch * 32 + q * 8];
      f16x8 bv2 = *(const f16x8*)&VS[(2 * 16 + m) * VSTR + ch * 32 + q * 8];
      f16x8 bv3 = *(const f16x8*)&VS[(3 * 16 + m) * VSTR + ch * 32 + q * 8];
      o0 = MFMA16(pa, bv0, o0);
      o1 = MFMA16(pa, bv1, o1);
      o2 = MFMA16(pa, bv2, o2);
      o3 = MFMA16(pa, bv3, o3);
    }

#pragma unroll
    for (int r = 0; r < 4; r++) {
      float s = l[r];
      s += __shfl_xor(s, 1);
      s += __shfl_xor(s, 2);
      s += __shfl_xor(s, 4);
      s += __shfl_xor(s, 8);
      l[r] = 1.0f / s;
    }

#pragma unroll
    for (int r = 0; r < 4; r++) {
      const int query = q0 + q * 4 + r;
      if (query < NN) {
        f16* orow = out + (size_t)(tok0 + query) * DD + h * HD;
        orow[m] = (f16)(o0[r] * l[r] + vmean[m]);
        orow[16 + m] = (f16)(o1[r] * l[r] + vmean[16 + m]);
        orow[32 + m] = (f16)(o2[r] * l[r] + vmean[32 + m]);
        orow[48 + m] = (f16)(o3[r] * l[r] + vmean[48 + m]);
      }
    }
  }
}

// ---------------------------------------------------------------------------
extern "C" void kernel_launch(void* const* d_in, const int* in_sizes, int n_in,
                              void* d_out, int out_size, void* d_ws,
                              size_t ws_size, hipStream_t stream) {
  (void)in_sizes;
  (void)n_in;
  (void)out_size;
  (void)ws_size;
  const float* x      = (const float*)d_in[0];
  const float* w_qkv  = (const float*)d_in[3];
  const float* w_proj = (const float*)d_in[4];
  const float* b_proj = (const float*)d_in[5];
  float* out = (float*)d_out;

  // workspace: qkvh (fp16 MM*D3, tile layout) | xh (fp16 MM*DD, reused for
  //            attn out) | wqkvT | wprojT   (~82 MB total)
  char* ws = (char*)d_ws;
  f16* qkvh = (f16*)ws;
  f16* xh = (f16*)(ws + (size_t)MM * D3 * 2);
  f16* wqkvT = xh + (size_t)MM * DD;
  f16* wprojT = wqkvT + (size_t)D3 * DD;

  // 0) fused prep: x->fp16, w_qkv^T->fp16, w_proj^T->fp16 (one launch)
  prep<<<PREP_BLOCKS, 256, 0, stream>>>(x, xh, w_qkv, wqkvT, w_proj, wprojT);
  // 1) qkv (fp16, attention tile layout) = x @ w_qkv  -- 256^2 8-phase, 32x32
  gemm256<1, 9><<<dim3(49 * 9), 512, 0, stream>>>(xh, wqkvT, qkvh, nullptr,
                                                  nullptr);
  // 2) MFMA attention + temporal mean -> fp16 token-major (overwrites xh)
  attn_mfma<<<BB * HH * TT, 512, 0, stream>>>(qkvh, xh);
  // 3) out = attn @ w_proj + b_proj (fp32 out) -- 256^2 8-phase, 32x32
  gemm256<0, 3><<<dim3(49 * 3), 512, 0, stream>>>(xh, wprojT, nullptr, out,
                                                  b_proj);
}

// Round 6
// 195.114 us; speedup vs baseline: 1.0836x; 1.0836x over previous
//
#include <hip/hip_runtime.h>
#include <math.h>

// Problem constants (fixed by setup_inputs)
#define BB 8
#define TT 8
#define NN 196
#define DD 768
#define HH 12
#define HD 64
#define TN (TT * NN)   // 1568
#define MM (BB * TN)   // 12544
#define D3 (3 * DD)    // 2304

typedef _Float16 f16;
typedef _Float16 f16x8 __attribute__((ext_vector_type(8)));
typedef _Float16 f16x4 __attribute__((ext_vector_type(4)));
typedef float f32x4 __attribute__((ext_vector_type(4)));
typedef unsigned int u32;

// async global->LDS, 16B per lane; LDS dest must be wave-uniform base + lane*16
#define GLDS16(gp, lp)                                                        \
  __builtin_amdgcn_global_load_lds(                                           \
      (const __attribute__((address_space(1))) u32*)(gp),                     \
      (__attribute__((address_space(3))) u32*)(lp), 16, 0, 0)

#define MFMA16(a, b, c) __builtin_amdgcn_mfma_f32_16x16x32_f16(a, b, c, 0, 0, 0)
#define SBAR() __builtin_amdgcn_s_barrier()
#define SCHED() __builtin_amdgcn_sched_barrier(0)
#define PBAR()  do { SCHED(); SBAR(); SCHED(); } while (0)

// ---------------------------------------------------------------------------
// 256x256 8-phase fp16 GEMM template, K = 768 fixed (both GEMMs share it).
// R6: exact R4 version restored (16x16x32). R5's 32x32x16 experiment fired
// its pre-registered failure mode: SQ_LDS_BANK_CONFLICT 0 -> 4.06M (~4 extra
// cycles per fragment ds_read_b128) — the chunk-XOR swizzle is conflict-free
// only for the 16-row x 4-chunk read geometry. Do not switch shapes again
// without a re-derived swizzle proven on hardware.
// C = A[12544][768] @ Bt[NTN*256][768]^T
// MODE 1 (qkv): fp16 out scattered to qkv tile layout; NTN=9 (441 blocks)
// MODE 0 (proj): fp32 out token-major + bias;          NTN=3 (147 blocks)
// 512 threads = 8 waves (2M x 4N), per-wave 128x64 output = acc[8][4] f32x4.
// LDS 128 KiB: As/Bs = 2 dbuf x [256][64] f16, chunk-XOR swizzle by (row&7)
// absorbed into the global source address (conflict-free ds_read_b128).
// Schedule per K-tile t (4 phases, quadrants; raw s_barrier, counted vmcnt):
//   F1: read af(mi0-3)+bf01 | stage A-h0(t+1)->buf^1 | bar | 16 MFMA | bar
//   F2: read bf23           | stage A-h1(t+1)->buf^1 | bar | 16 MFMA | bar
//   F3: read af(mi4-7)      | stage B-h0(t+2)->buf   | bar | 16 MFMA | bar
//   F4: (no reads)          | stage B-h1(t+2)->buf   | vmcnt(4) | bar | 16 | bar
// B-halves of the in-use buffer are fully read by F2's closing barrier, so
// F3/F4's DMA into them is race-free. vmcnt(4) leaves exactly the two t+2
// B half-tiles in flight across the tile boundary (never drains to 0).
// Tail staging clamps the tile index (uniform vmcnt counts; dups are L2-hot
// and never read).
// ---------------------------------------------------------------------------
#define GK DD    // 768
#define GNT 12   // K tiles of 64

template <int MI0, int NJ0>
__device__ __forceinline__ void quad(f32x4 (&acc)[8][4],
                                     const f16x8 (&af)[4][2],
                                     const f16x8 (&bf)[2][2]) {
  __builtin_amdgcn_s_setprio(1);
#pragma unroll
  for (int i = 0; i < 4; i++)
#pragma unroll
    for (int j = 0; j < 2; j++) {
      acc[MI0 + i][NJ0 + j] = MFMA16(af[i][0], bf[j][0], acc[MI0 + i][NJ0 + j]);
      acc[MI0 + i][NJ0 + j] = MFMA16(af[i][1], bf[j][1], acc[MI0 + i][NJ0 + j]);
    }
  __builtin_amdgcn_s_setprio(0);
}

template <int MODE, int NTN>
__global__ __launch_bounds__(512, 2) void gemm256(
    const f16* __restrict__ A, const f16* __restrict__ Bt,
    f16* __restrict__ C16, float* __restrict__ C32,
    const float* __restrict__ bias) {
  __shared__ f16 As[2 * 256 * 64];
  __shared__ f16 Bs[2 * 256 * 64];

  // bijective XCD swizzle over 49*NTN blocks
  const int nwg = 49 * NTN;
  const int orig = blockIdx.x;
  const int xcd = orig & 7;
  const int inner = orig >> 3;
  const int qq = nwg >> 3;
  const int rr = nwg & 7;
  const int swzid =
      ((xcd < rr) ? xcd * (qq + 1) : rr * (qq + 1) + (xcd - rr) * qq) + inner;
  const int bm = (swzid / NTN) * 256;
  const int bn = (swzid % NTN) * 256;

  const int tid = threadIdx.x;
  const int lane = tid & 63;
  const int wave = tid >> 6;      // 0..7
  const int wy = wave >> 2;       // 0..1  (M half)
  const int wx = wave & 3;        // 0..3  (N quarter)
  const int m = lane & 15;
  const int q = lane >> 4;

  // --- staging: thread handles phys chunks {tid, tid+512} of each 128x64
  // half-tile; row = chunk>>3 (+64), phys slot = chunk&7,
  // logical chunk = slot ^ (row&7) pre-applied to the GLOBAL address.
  const int sr = tid >> 3;                 // 0..63
  const int sc = (tid & 7) ^ (sr & 7);
  const f16* gA = A + (size_t)(bm + sr) * GK + sc * 8;
  const f16* gB = Bt + (size_t)(bn + sr) * GK + sc * 8;
  f16* lA = &As[tid * 8];
  f16* lB = &Bs[tid * 8];

#define STAGE_A(db, h, tile)                                   \
  do {                                                         \
    const f16* _s = gA + (size_t)(h) * 128 * GK + (tile) * 64; \
    f16* _d = lA + (db) * 16384 + (h) * 8192;                  \
    GLDS16(_s, _d);                                            \
    GLDS16(_s + 64 * GK, _d + 4096);                           \
  } while (0)
#define STAGE_B(db, h, tile)                                   \
  do {                                                         \
    const f16* _s = gB + (size_t)(h) * 128 * GK + (tile) * 64; \
    f16* _d = lB + (db) * 16384 + (h) * 8192;                  \
    GLDS16(_s, _d);                                            \
    GLDS16(_s + 64 * GK, _d + 4096);                           \
  } while (0)

  // --- fragment read addressing (row&7 == m&7 for every fragment row)
  const int sw = m & 7;
  const int c0 = (q ^ sw) * 8;
  const int c1 = ((q + 4) ^ sw) * 8;
  const f16* rA = &As[(wy * 128 + m) * 64];
  const f16* rB = &Bs[(wx * 64 + m) * 64];

  // --- prologue: A(0),B(0) then B(1); allow B(1) (4 loads) outstanding
  STAGE_A(0, 0, 0);
  STAGE_A(0, 1, 0);
  STAGE_B(0, 0, 0);
  STAGE_B(0, 1, 0);
  STAGE_B(1, 0, 1);
  STAGE_B(1, 1, 1);

  f32x4 acc[8][4];
#pragma unroll
  for (int i = 0; i < 8; i++)
#pragma unroll
    for (int j = 0; j < 4; j++) acc[i][j] = (f32x4)0.0f;

  SCHED();
  asm volatile("s_waitcnt vmcnt(4)" ::: "memory");
  SCHED();
  SBAR();
  SCHED();

#pragma unroll 2
  for (int t = 0; t < GNT; ++t) {
    const int db = t & 1;
    const f16* pA = rA + db * 16384;
    const f16* pB = rB + db * 16384;
    const int tA = (t + 1 < GNT) ? t + 1 : GNT - 1;
    const int tB = (t + 2 < GNT) ? t + 2 : GNT - 1;

    f16x8 af[4][2], bf0[2][2], bf1[2][2];

    // ---- Phase 1: af(mi0-3) + bf(ni0-1); stage A-h0(t+1)
#pragma unroll
    for (int i = 0; i < 4; i++) {
      af[i][0] = *(const f16x8*)(pA + i * 1024 + c0);
      af[i][1] = *(const f16x8*)(pA + i * 1024 + c1);
    }
#pragma unroll
    for (int j = 0; j < 2; j++) {
      bf0[j][0] = *(const f16x8*)(pB + j * 1024 + c0);
      bf0[j][1] = *(const f16x8*)(pB + j * 1024 + c1);
    }
    STAGE_A(db ^ 1, 0, tA);
    PBAR();
    quad<0, 0>(acc, af, bf0);
    PBAR();

    // ---- Phase 2: bf(ni2-3); stage A-h1(t+1)
#pragma unroll
    for (int j = 0; j < 2; j++) {
      bf1[j][0] = *(const f16x8*)(pB + (2 + j) * 1024 + c0);
      bf1[j][1] = *(const f16x8*)(pB + (2 + j) * 1024 + c1);
    }
    STAGE_A(db ^ 1, 1, tA);
    PBAR();
    quad<0, 2>(acc, af, bf1);
    PBAR();

    // ---- Phase 3: af(mi4-7); stage B-h0(t+2) into CURRENT buf (B reads done)
#pragma unroll
    for (int i = 0; i < 4; i++) {
      af[i][0] = *(const f16x8*)(pA + (4 + i) * 1024 + c0);
      af[i][1] = *(const f16x8*)(pA + (4 + i) * 1024 + c1);
    }
    STAGE_B(db, 0, tB);
    PBAR();
    quad<4, 2>(acc, af, bf1);
    PBAR();

    // ---- Phase 4: stage B-h1(t+2); counted vmcnt (A(t+1)+older must land,
    //      B(t+2) pair stays in flight)
    STAGE_B(db, 1, tB);
    SCHED();
    asm volatile("s_waitcnt vmcnt(4)" ::: "memory");
    PBAR();
    quad<4, 0>(acc, af, bf0);
    PBAR();
  }

  // ---- epilogue
  const int col0 = bn + wx * 64;
  if constexpr (MODE == 1) {
    // qkv scatter to attention tile layout
#pragma unroll
    for (int mi = 0; mi < 8; mi++) {
      const int row0 = bm + wy * 128 + mi * 16 + q * 4;
#pragma unroll
      for (int r = 0; r < 4; r++) {
        const int token = row0 + r;
        const int f = token / NN;
        const int n = token - f * NN;
        f16* fb = C16 + ((size_t)f * (HH * 3)) * (NN * 64) + n * 64;
#pragma unroll
        for (int ni = 0; ni < 4; ni++) {
          const int col = col0 + ni * 16 + m;
          const int qt = col / DD;
          const int rem = col - qt * DD;
          const int hh = rem >> 6;
          const int d = rem & 63;
          fb[(size_t)(hh * 3 + qt) * (NN * 64) + d] = (f16)acc[mi][ni][r];
        }
      }
    }
  } else {
    // proj: token-major fp32 + bias
#pragma unroll
    for (int mi = 0; mi < 8; mi++) {
      const int row0 = bm + wy * 128 + mi * 16 + q * 4;
#pragma unroll
      for (int ni = 0; ni < 4; ni++) {
        const int col = col0 + ni * 16 + m;
        const float bv = bias[col];
#pragma unroll
        for (int r = 0; r < 4; r++)
          C32[(size_t)(row0 + r) * (NTN * 256) + col] = acc[mi][ni][r] + bv;
      }
    }
  }
#undef STAGE_A
#undef STAGE_B
}

// ---------------------------------------------------------------------------
// prep: fused input conversion + both weight transposes (one launch).
// segment 0: x fp32 -> xh fp16 (grid-stride, float4)
// segment 1: w_qkv [768][2304] fp32 -> wqkvT [2304][768] fp16
// segment 2: w_proj [768][768] fp32 -> wprojT [768][768] fp16
// ---------------------------------------------------------------------------
#define CONV_BLOCKS 2048
#define TQ_BLOCKS ((D3 / 32) * (DD / 32))  // 72*24 = 1728
#define TP_BLOCKS ((DD / 32) * (DD / 32))  // 24*24 = 576
#define PREP_BLOCKS (CONV_BLOCKS + TQ_BLOCKS + TP_BLOCKS)  // 4352

__global__ __launch_bounds__(256) void prep(
    const float* __restrict__ x, f16* __restrict__ xh,
    const float* __restrict__ w_qkv, f16* __restrict__ wqkvT,
    const float* __restrict__ w_proj, f16* __restrict__ wprojT) {
  __shared__ float tileS[32][33];
  const int bid = blockIdx.x;
  if (bid < CONV_BLOCKS) {
    const int n4 = MM * DD / 4;
    int i = bid * 256 + threadIdx.x;
    const int stride = CONV_BLOCKS * 256;
    for (; i < n4; i += stride) {
      float4 f = ((const float4*)x)[i];
      f16x4 h;
      h[0] = (f16)f.x;
      h[1] = (f16)f.y;
      h[2] = (f16)f.z;
      h[3] = (f16)f.w;
      ((f16x4*)xh)[i] = h;
    }
    return;
  }
  const float* W;
  f16* Wt;
  int Ncol, id;
  if (bid < CONV_BLOCKS + TQ_BLOCKS) {
    id = bid - CONV_BLOCKS;
    W = w_qkv;
    Wt = wqkvT;
    Ncol = D3;
  } else {
    id = bid - CONV_BLOCKS - TQ_BLOCKS;
    W = w_proj;
    Wt = wprojT;
    Ncol = DD;
  }
  const int nx = Ncol / 32;
  const int n0 = (id % nx) * 32;
  const int k0 = (id / nx) * 32;
  const int tx = threadIdx.x & 31, ty = threadIdx.x >> 5;
#pragma unroll
  for (int i = 0; i < 4; i++)
    tileS[ty + i * 8][tx] = W[(size_t)(k0 + ty + i * 8) * Ncol + n0 + tx];
  __syncthreads();
#pragma unroll
  for (int i = 0; i < 4; i++)
    Wt[(size_t)(n0 + ty + i * 8) * DD + k0 + tx] = (f16)tileS[tx][ty + i * 8];
}

// ---------------------------------------------------------------------------
// MFMA attention per (b,h,t), 512 threads (8 waves).
// R6: + s_setprio(1/0) around the QK^T and PV MFMA clusters (T5). Attn's 8
// waves run independent q-tiles with no intra-loop barriers — the measured
// +4-7% setprio regime (m191), unlike lockstep GEMM where it's null.
// ---------------------------------------------------------------------------
#define VSTR 232

__global__ __launch_bounds__(512, 4) void attn_mfma(
    const f16* __restrict__ qkv, f16* __restrict__ out) {
  __shared__ f16 KS[196 * 64];
  __shared__ f16 VS[64 * VSTR];
  __shared__ __align__(16) f16 PS[8 * 16 * 40];
  __shared__ float vmean[64];
  float* red = (float*)PS;  // red used strictly before PS (barrier between)

  const int bi = blockIdx.x;  // b*H*T + h*T + t
  const int t = bi % TT;
  const int h = (bi / TT) % HH;
  const int b = bi / (TT * HH);
  const int frame = b * TT + t;
  const int tok0 = frame * NN;

  const f16* Qb = qkv + (size_t)(frame * HH + h) * 3 * NN * 64;
  const f16* Kb = Qb + NN * 64;
  const f16* Vb = Qb + 2 * NN * 64;

  const int tid = threadIdx.x;
  const int lane = tid & 63;
  const int wave = tid >> 6;  // 0..7
  const int m = lane & 15;
  const int q = lane >> 4;

#pragma unroll
  for (int it = 0; it < 3; it++) {
    int chunk = tid + it * 512;
    int row = chunk >> 3, pc = chunk & 7;
    int c = pc ^ (row & 7);
    GLDS16(Kb + row * 64 + c * 8, &KS[chunk * 8]);
  }
  if (tid < 32) {
    int chunk = 1536 + tid;
    int row = chunk >> 3, pc = chunk & 7;
    int c = pc ^ (row & 7);
    *(f16x8*)&KS[chunk * 8] = *(const f16x8*)(Kb + row * 64 + c * 8);
  }

  for (int idx = tid; idx < 64 * 9; idx += 512) {
    int d = idx / 9, c = idx % 9;
    *(f16x4*)&VS[d * VSTR + 196 + c * 4] = (f16x4){0, 0, 0, 0};
  }

  const int vd = tid & 63;
  const int kb = tid >> 6;
  float vpart = 0.0f;
  if (kb < 7) {
#pragma unroll
    for (int it = 0; it < 7; it++) {
      int k0 = kb * 28 + it * 4;
      f16x4 pk;
#pragma unroll
      for (int j = 0; j < 4; j++) {
        f16 v = Vb[(k0 + j) * 64 + vd];
        pk[j] = v;
        vpart += (float)v;
      }
      *(f16x4*)&VS[vd * VSTR + k0] = pk;
    }
  }
  red[tid] = vpart;
  __syncthreads();
  if (tid < 64) {
    float s = 0.0f;
#pragma unroll
    for (int g = 0; g < 8; g++) s += red[tid + 64 * g];
    vmean[tid] = s * (1.0f / (float)NN);
  }
  __syncthreads();

  f16* PSw = &PS[wave * 640];

  for (int qt = wave; qt < 13; qt += 8) {
    const int q0 = qt * 16;
    int qrow = q0 + m;
    if (qrow > NN - 1) qrow = NN - 1;
    const f16* qbase = Qb + qrow * 64;
    f16x8 aq0 = *(const f16x8*)(qbase + q * 8);
    f16x8 aq1 = *(const f16x8*)(qbase + 32 + q * 8);

    f32x4 o0 = (f32x4)0.0f, o1 = (f32x4)0.0f, o2 = (f32x4)0.0f,
          o3 = (f32x4)0.0f;
    float l[4] = {0.0f, 0.0f, 0.0f, 0.0f};

    for (int ch = 0; ch < 7; ch++) {
      const int keyA = ch * 32 + m;
      const int keyB = keyA + 16;
      const int kA = keyA > 195 ? 195 : keyA;
      const int kB = keyB > 195 ? 195 : keyB;
      const int swA = kA & 7, swB = kB & 7;
      f16x8 b00 = *(const f16x8*)&KS[kA * 64 + ((q ^ swA) * 8)];
      f16x8 b01 = *(const f16x8*)&KS[kA * 64 + (((q + 4) ^ swA) * 8)];
      f16x8 b10 = *(const f16x8*)&KS[kB * 64 + ((q ^ swB) * 8)];
      f16x8 b11 = *(const f16x8*)&KS[kB * 64 + (((q + 4) ^ swB) * 8)];
      f32x4 z = (f32x4)0.0f;
      __builtin_amdgcn_s_setprio(1);
      f32x4 s0 = MFMA16(aq0, b00, z);
      s0 = MFMA16(aq1, b01, s0);
      f32x4 s1 = MFMA16(aq0, b10, z);
      s1 = MFMA16(aq1, b11, s1);
      __builtin_amdgcn_s_setprio(0);

      const bool v0 = keyA < NN;
      const bool v1 = keyB < NN;
#pragma unroll
      for (int r = 0; r < 4; r++) {
        float p0 = v0 ? __expf(s0[r] * 0.125f) : 0.0f;
        float p1 = v1 ? __expf(s1[r] * 0.125f) : 0.0f;
        l[r] += p0 + p1;
        PSw[(q * 4 + r) * 40 + m] = (f16)p0;
        PSw[(q * 4 + r) * 40 + 16 + m] = (f16)p1;
      }
      f16x8 pa = *(const f16x8*)&PSw[m * 40 + q * 8];
      f16x8 bv0 = *(const f16x8*)&VS[(0 * 16 + m) * VSTR + ch * 32 + q * 8];
      f16x8 bv1 = *(const f16x8*)&VS[(1 * 16 + m) * VSTR + ch * 32 + q * 8];
      f16x8 bv2 = *(const f16x8*)&VS[(2 * 16 + m) * VSTR + ch * 32 + q * 8];
      f16x8 bv3 = *(const f16x8*)&VS[(3 * 16 + m) * VSTR + ch * 32 + q * 8];
      __builtin_amdgcn_s_setprio(1);
      o0 = MFMA16(pa, bv0, o0);
      o1 = MFMA16(pa, bv1, o1);
      o2 = MFMA16(pa, bv2, o2);
      o3 = MFMA16(pa, bv3, o3);
      __builtin_amdgcn_s_setprio(0);
    }

#pragma unroll
    for (int r = 0; r < 4; r++) {
      float s = l[r];
      s += __shfl_xor(s, 1);
      s += __shfl_xor(s, 2);
      s += __shfl_xor(s, 4);
      s += __shfl_xor(s, 8);
      l[r] = 1.0f / s;
    }

#pragma unroll
    for (int r = 0; r < 4; r++) {
      const int query = q0 + q * 4 + r;
      if (query < NN) {
        f16* orow = out + (size_t)(tok0 + query) * DD + h * HD;
        orow[m] = (f16)(o0[r] * l[r] + vmean[m]);
        orow[16 + m] = (f16)(o1[r] * l[r] + vmean[16 + m]);
        orow[32 + m] = (f16)(o2[r] * l[r] + vmean[32 + m]);
        orow[48 + m] = (f16)(o3[r] * l[r] + vmean[48 + m]);
      }
    }
  }
}

// ---------------------------------------------------------------------------
extern "C" void kernel_launch(void* const* d_in, const int* in_sizes, int n_in,
                              void* d_out, int out_size, void* d_ws,
                              size_t ws_size, hipStream_t stream) {
  (void)in_sizes;
  (void)n_in;
  (void)out_size;
  (void)ws_size;
  const float* x      = (const float*)d_in[0];
  const float* w_qkv  = (const float*)d_in[3];
  const float* w_proj = (const float*)d_in[4];
  const float* b_proj = (const float*)d_in[5];
  float* out = (float*)d_out;

  // workspace: qkvh (fp16 MM*D3, tile layout) | xh (fp16 MM*DD, reused for
  //            attn out) | wqkvT | wprojT   (~82 MB total)
  char* ws = (char*)d_ws;
  f16* qkvh = (f16*)ws;
  f16* xh = (f16*)(ws + (size_t)MM * D3 * 2);
  f16* wqkvT = xh + (size_t)MM * DD;
  f16* wprojT = wqkvT + (size_t)D3 * DD;

  // 0) fused prep: x->fp16, w_qkv^T->fp16, w_proj^T->fp16 (one launch)
  prep<<<PREP_BLOCKS, 256, 0, stream>>>(x, xh, w_qkv, wqkvT, w_proj, wprojT);
  // 1) qkv (fp16, attention tile layout) = x @ w_qkv  -- 256^2 8-phase
  gemm256<1, 9><<<dim3(49 * 9), 512, 0, stream>>>(xh, wqkvT, qkvh, nullptr,
                                                  nullptr);
  // 2) MFMA attention + temporal mean -> fp16 token-major (overwrites xh)
  attn_mfma<<<BB * HH * TT, 512, 0, stream>>>(qkvh, xh);
  // 3) out = attn @ w_proj + b_proj (fp32 out) -- 256^2 8-phase, single round
  gemm256<0, 3><<<dim3(49 * 3), 512, 0, stream>>>(xh, wprojT, nullptr, out,
                                                  b_proj);
}